// Round 2
// baseline (29372.018 us; speedup 1.0000x reference)
//
#include <hip/hip_runtime.h>
#include <math.h>

// Sizes (fixed by the problem)
#define BATCH   64
#define SEQ     512
#define NIN     512
#define NHID    1024
#define NOUT    512

// ---------------- Tiled fp32 GEMM with bias: C[M,N] = A[M,K] @ B[K,N] + bias[N]
#define BM 64
#define BN 64
#define BK 16

__global__ __launch_bounds__(256) void gemm_bias(
    const float* __restrict__ A, const float* __restrict__ B,
    const float* __restrict__ bias, float* __restrict__ C,
    int M, int N, int K) {
  __shared__ float As[BK][BM + 4];
  __shared__ float Bs[BK][BN + 4];

  const int tid = threadIdx.x;
  const int bx = blockIdx.x;
  const int by = blockIdx.y;

  const int tm = (tid / 16) * 4;
  const int tn = (tid % 16) * 4;

  const int ar = tid / 4;
  const int ac = (tid % 4) * 4;
  const int br = tid / 16;
  const int bc = (tid % 16) * 4;

  float acc[4][4] = {};

  for (int k0 = 0; k0 < K; k0 += BK) {
    float4 av = *(const float4*)&A[(size_t)(by * BM + ar) * K + k0 + ac];
    As[ac + 0][ar] = av.x;
    As[ac + 1][ar] = av.y;
    As[ac + 2][ar] = av.z;
    As[ac + 3][ar] = av.w;
    float4 bv = *(const float4*)&B[(size_t)(k0 + br) * N + bx * BN + bc];
    *(float4*)&Bs[br][bc] = bv;
    __syncthreads();

#pragma unroll
    for (int k = 0; k < BK; ++k) {
      float4 a4 = *(const float4*)&As[k][tm];
      float4 b4 = *(const float4*)&Bs[k][tn];
      float ae[4] = {a4.x, a4.y, a4.z, a4.w};
      float be[4] = {b4.x, b4.y, b4.z, b4.w};
#pragma unroll
      for (int i = 0; i < 4; ++i)
#pragma unroll
        for (int j = 0; j < 4; ++j)
          acc[i][j] += ae[i] * be[j];
    }
    __syncthreads();
  }

  const float4 bb = *(const float4*)&bias[bx * BN + tn];
#pragma unroll
  for (int i = 0; i < 4; ++i) {
    float4 o;
    o.x = acc[i][0] + bb.x;
    o.y = acc[i][1] + bb.y;
    o.z = acc[i][2] + bb.z;
    o.w = acc[i][3] + bb.w;
    *(float4*)&C[(size_t)(by * BM + tm + i) * N + bx * BN + tn] = o;
  }
}

// ---------------- Cooperative weight-stationary scan ----------------
// Grid: 256 blocks = 8 batch-groups x 32 column-chunks. Block (bg, jc):
//  - holds Wh[kseg*128 .. +127][jc*32+j] in 128 VGPRs per thread (read once)
//  - per step: stages h_{s} (= xi[., s-1, .] in-place) rows of its 8 batches
//    into LDS, computes partial dots (K split 8-ways across threads),
//    LDS-reduces, applies tanh/relu, writes h into xi[., s, .] in place.
//  - syncs only its 32-block group via monotonic device-scope counter.
#define GROUPS 8
#define BPG    32   // blocks per group (column chunks)
#define BPERG  8    // batches per group

__global__ __launch_bounds__(256, 1) void rnn_scan_coop(
    const float* __restrict__ Wh, float* __restrict__ xi,
    unsigned int* ctr) {
  __shared__ float hs[BPERG][NHID];        // 32 KB
  __shared__ float red[8][BPERG][32];      // 8 KB

  const int tid  = threadIdx.x;
  const int bg   = blockIdx.x >> 5;   // 0..7
  const int jc   = blockIdx.x & 31;   // 0..31
  const int kseg = tid >> 5;          // 0..7  (K-split)
  const int j    = tid & 31;          // column within chunk
  const int jglob = jc * 32 + j;
  const int kbase = kseg * 128;

  // Preload this thread's Wh sliver: 128 consecutive k, one column.
  float wreg[128];
#pragma unroll
  for (int k2 = 0; k2 < 128; ++k2)
    wreg[k2] = Wh[(size_t)(kbase + k2) * NHID + jglob];

  // Coordinates for the reduce/output phase: thread -> (batch ob, col oj)
  const int ob = tid >> 5;            // 0..7
  const int oj = tid & 31;
  const int obglob = bg * BPERG + ob;

  for (int s = 0; s < SEQ; ++s) {
    float sum = 0.f;
    if (s > 0) {
      // Stage h_s rows (written by whole group last step) into LDS.
#pragma unroll
      for (int i = 0; i < BPERG; ++i) {
        const float* src = xi + ((size_t)(bg * BPERG + i) * SEQ + (s - 1)) * NHID;
        float4 v = *(const float4*)(src + tid * 4);
        *(float4*)&hs[i][tid * 4] = v;
      }
      __syncthreads();

      float acc[BPERG] = {};
#pragma unroll
      for (int kq = 0; kq < 32; ++kq) {
#pragma unroll
        for (int b = 0; b < BPERG; ++b) {
          float4 h4 = *(const float4*)&hs[b][kbase + kq * 4];
          acc[b] = fmaf(h4.x, wreg[kq * 4 + 0], acc[b]);
          acc[b] = fmaf(h4.y, wreg[kq * 4 + 1], acc[b]);
          acc[b] = fmaf(h4.z, wreg[kq * 4 + 2], acc[b]);
          acc[b] = fmaf(h4.w, wreg[kq * 4 + 3], acc[b]);
        }
      }
#pragma unroll
      for (int b = 0; b < BPERG; ++b)
        red[kseg][b][j] = acc[b];
      __syncthreads();
#pragma unroll
      for (int ks = 0; ks < 8; ++ks)
        sum += red[ks][ob][oj];
    }

    // h_{s+1}[obglob][jglob'] = relu(tanh(xi_t + sum)), written in place.
    float* prow = xi + ((size_t)obglob * SEQ + s) * NHID;
    float v = prow[jc * 32 + oj];
    float hn = fmaxf(tanhf(v + sum), 0.f);
    prow[jc * 32 + oj] = hn;

    // ---- group barrier (monotonic counter, device scope) ----
    __threadfence();
    if (tid == 0) {
      __hip_atomic_fetch_add(&ctr[bg], 1u, __ATOMIC_RELEASE, __HIP_MEMORY_SCOPE_AGENT);
      const unsigned int target = (unsigned int)(BPG * (s + 1));
      while (__hip_atomic_load(&ctr[bg], __ATOMIC_ACQUIRE, __HIP_MEMORY_SCOPE_AGENT) < target)
        __builtin_amdgcn_s_sleep(2);
    }
    __syncthreads();
    __threadfence();
  }
}

extern "C" void kernel_launch(void* const* d_in, const int* in_sizes, int n_in,
                              void* d_out, int out_size, void* d_ws, size_t ws_size,
                              hipStream_t stream) {
  const float* x  = (const float*)d_in[0];  // [64,512,512]
  const float* Wi = (const float*)d_in[1];  // [512,1024]
  const float* bi = (const float*)d_in[2];  // [1024]
  const float* Wh = (const float*)d_in[3];  // [1024,1024]
  const float* Wo = (const float*)d_in[4];  // [1024,512]
  const float* bo = (const float*)d_in[5];  // [512]
  float* out = (float*)d_out;               // [64,512,512]
  float* xi  = (float*)d_ws;                // [64,512,1024] = 128 MB scratch

  // Barrier counters live in the head of d_out; the final GEMM (runs after
  // the scan) overwrites them with real output. Zeroed every launch.
  unsigned int* ctr = (unsigned int*)d_out;

  const int M = BATCH * SEQ;  // 32768

  dim3 blk(256);
  hipMemsetAsync(ctr, 0, GROUPS * sizeof(unsigned int), stream);
  // xi = x @ Wi + bi
  gemm_bias<<<dim3(NHID / BN, M / BM), blk, 0, stream>>>(x, Wi, bi, xi, M, NHID, NIN);
  // sequential scan (cooperative: all 256 blocks co-resident)
  {
    const float* Wh_p = Wh;
    float* xi_p = xi;
    unsigned int* ctr_p = ctr;
    void* args[3] = {(void*)&Wh_p, (void*)&xi_p, (void*)&ctr_p};
    hipLaunchCooperativeKernel((const void*)rnn_scan_coop, dim3(GROUPS * BPG),
                               dim3(256), args, 0, stream);
  }
  // y = h @ Wo + bo
  gemm_bias<<<dim3(NOUT / BN, M / BM), blk, 0, stream>>>(xi, Wo, bo, out, M, NOUT, NHID);
}

// Round 3
// 8662.611 us; speedup vs baseline: 3.3907x; 3.3907x over previous
//
#include <hip/hip_runtime.h>
#include <math.h>

// Sizes (fixed by the problem)
#define BATCH   64
#define SEQ     512
#define NIN     512
#define NHID    1024
#define NOUT    512

// ---------------- Tiled fp32 GEMM with bias: C[M,N] = A[M,K] @ B[K,N] + bias[N]
#define BM 64
#define BN 64
#define BK 16

__global__ __launch_bounds__(256) void gemm_bias(
    const float* __restrict__ A, const float* __restrict__ B,
    const float* __restrict__ bias, float* __restrict__ C,
    int M, int N, int K) {
  __shared__ float As[BK][BM + 4];
  __shared__ float Bs[BK][BN + 4];

  const int tid = threadIdx.x;
  const int bx = blockIdx.x;
  const int by = blockIdx.y;

  const int tm = (tid / 16) * 4;
  const int tn = (tid % 16) * 4;

  const int ar = tid / 4;
  const int ac = (tid % 4) * 4;
  const int br = tid / 16;
  const int bc = (tid % 16) * 4;

  float acc[4][4] = {};

  for (int k0 = 0; k0 < K; k0 += BK) {
    float4 av = *(const float4*)&A[(size_t)(by * BM + ar) * K + k0 + ac];
    As[ac + 0][ar] = av.x;
    As[ac + 1][ar] = av.y;
    As[ac + 2][ar] = av.z;
    As[ac + 3][ar] = av.w;
    float4 bv = *(const float4*)&B[(size_t)(k0 + br) * N + bx * BN + bc];
    *(float4*)&Bs[br][bc] = bv;
    __syncthreads();

#pragma unroll
    for (int k = 0; k < BK; ++k) {
      float4 a4 = *(const float4*)&As[k][tm];
      float4 b4 = *(const float4*)&Bs[k][tn];
      float ae[4] = {a4.x, a4.y, a4.z, a4.w};
      float be[4] = {b4.x, b4.y, b4.z, b4.w};
#pragma unroll
      for (int i = 0; i < 4; ++i)
#pragma unroll
        for (int j = 0; j < 4; ++j)
          acc[i][j] += ae[i] * be[j];
    }
    __syncthreads();
  }

  const float4 bb = *(const float4*)&bias[bx * BN + tn];
#pragma unroll
  for (int i = 0; i < 4; ++i) {
    float4 o;
    o.x = acc[i][0] + bb.x;
    o.y = acc[i][1] + bb.y;
    o.z = acc[i][2] + bb.z;
    o.w = acc[i][3] + bb.w;
    *(float4*)&C[(size_t)(by * BM + tm + i) * N + bx * BN + tn] = o;
  }
}

// ---------------- Cooperative weight-stationary scan, v3 ----------------
// 256 blocks = 8 batch-groups x 32 col-chunks; 256 threads.
// Thread (c4 = tid&7, kseg = tid>>3): holds Wh[kseg*32 .. +31][col4] in
// float4 w[32] (128 VGPRs, SROA-safe 32-iter preload). Partial dot over its
// 32-k slice for 8 batches x 4 cols; k-split reduced via swizzled LDS
// transpose. Cross-block h exchange + barrier use RELAXED agent-scope
// atomics only (per-op cache-scope bits; NO threadfence -> no buffer_wbl2).
#define GROUPS 8
#define BPG    32   // blocks per group (column chunks)
#define BPERG  8    // batches per group

#define FMA4(hv, wv4, accv)              \
  accv.x = fmaf(hv, wv4.x, accv.x);      \
  accv.y = fmaf(hv, wv4.y, accv.y);      \
  accv.z = fmaf(hv, wv4.z, accv.z);      \
  accv.w = fmaf(hv, wv4.w, accv.w);

__global__ __launch_bounds__(256, 1) void rnn_scan_ws(
    const float* __restrict__ Wh, float* __restrict__ xi,
    unsigned int* ctr) {
  __shared__ float hs[BPERG * NHID];   // 32 KB staged h, XOR-swizzled on k
  __shared__ float P[256 * 32];        // 32 KB partial sums

  const int tid  = threadIdx.x;
  const int bg   = blockIdx.x >> 5;   // 0..7  batch group
  const int jc   = blockIdx.x & 31;   // 0..31 column chunk (32 cols)
  const int c4   = tid & 7;           // column quad within chunk
  const int kseg = tid >> 3;          // 0..31 k-slice (32 k each)
  const int colbase = jc * 32 + c4 * 4;
  const int hswz  = (kseg & 7) << 2;        // read-side LDS swizzle
  const int stswz = ((tid >> 5) & 7) << 2;  // write-side LDS swizzle
  const int ob   = tid >> 5;          // output batch (0..7)
  const int ocol = tid & 31;          // output col within chunk
  const int oc4  = ocol >> 2;
  const int oce  = ocol & 3;

  // Wh sliver in registers: 32 float4 vector loads, fully unrolled.
  float4 w[32];
#pragma unroll
  for (int kk = 0; kk < 32; ++kk)
    w[kk] = *(const float4*)&Wh[(size_t)(kseg * 32 + kk) * NHID + colbase];

  for (int s = 0; s < SEQ; ++s) {
    float4 acc[BPERG];
#pragma unroll
    for (int b = 0; b < BPERG; ++b) acc[b] = make_float4(0.f, 0.f, 0.f, 0.f);

    if (s > 0) {
      // Stage h_{s-1} (8 rows x 1024) into swizzled LDS via agent-scope loads.
#pragma unroll
      for (int q = 0; q < 32; ++q) {
        const int b = q >> 2;
        const int k = (q & 3) * 256 + tid;
        const float* src =
            xi + ((size_t)(bg * BPERG + b) * SEQ + (s - 1)) * NHID + k;
        float v = __hip_atomic_load((float*)src, __ATOMIC_RELAXED,
                                    __HIP_MEMORY_SCOPE_AGENT);
        hs[b * NHID + (k ^ stswz)] = v;
      }
      __syncthreads();

      // Partial matvec over this thread's 32-k slice.
#pragma unroll
      for (int b = 0; b < BPERG; ++b) {
#pragma unroll
        for (int kq = 0; kq < 8; ++kq) {
          const float4 h4 =
              *(const float4*)&hs[b * NHID + kseg * 32 + ((kq * 4) ^ hswz)];
          FMA4(h4.x, w[kq * 4 + 0], acc[b]);
          FMA4(h4.y, w[kq * 4 + 1], acc[b]);
          FMA4(h4.z, w[kq * 4 + 2], acc[b]);
          FMA4(h4.w, w[kq * 4 + 3], acc[b]);
        }
      }
      __syncthreads();  // hs reads done before P (re)written below... (P disjoint, but keep ordering simple)
    }

    // Write partials to LDS (bank-swizzled), reduce 32-way per output.
    {
      const int u = kseg * 8 + c4;
      const int sw = (((kseg & 7) ^ c4)) << 2;
#pragma unroll
      for (int b = 0; b < BPERG; ++b)
        *(float4*)&P[u * 32 + ((b * 4) ^ sw)] = acc[b];
    }
    __syncthreads();

    float sum = 0.f;
#pragma unroll
    for (int q = 0; q < 32; ++q) {
      const int uu = q * 8 + oc4;
      const int sw2 = ((q & 7) ^ oc4) << 2;
      sum += P[uu * 32 + ((ob * 4 + oce) ^ sw2)];
    }

    // Activation + in-place store of h_s (agent-scope, write-through).
    float* prow =
        xi + ((size_t)(bg * BPERG + ob) * SEQ + s) * NHID + jc * 32 + ocol;
    const float v = *prow;  // own xi value, never touched by other blocks
    const float hn = fmaxf(tanhf(v + sum), 0.f);
    __hip_atomic_store(prow, hn, __ATOMIC_RELAXED, __HIP_MEMORY_SCOPE_AGENT);

    // Group barrier: syncthreads drains vmcnt(0) (stores at LLC), then
    // monotonic relaxed counter at agent scope.
    __syncthreads();
    if (tid == 0) {
      __hip_atomic_fetch_add(&ctr[bg], 1u, __ATOMIC_RELAXED,
                             __HIP_MEMORY_SCOPE_AGENT);
      const unsigned int target = (unsigned int)(BPG * (s + 1));
      while (__hip_atomic_load(&ctr[bg], __ATOMIC_RELAXED,
                               __HIP_MEMORY_SCOPE_AGENT) < target)
        __builtin_amdgcn_s_sleep(1);
    }
    __syncthreads();
  }
}

extern "C" void kernel_launch(void* const* d_in, const int* in_sizes, int n_in,
                              void* d_out, int out_size, void* d_ws, size_t ws_size,
                              hipStream_t stream) {
  const float* x  = (const float*)d_in[0];  // [64,512,512]
  const float* Wi = (const float*)d_in[1];  // [512,1024]
  const float* bi = (const float*)d_in[2];  // [1024]
  const float* Wh = (const float*)d_in[3];  // [1024,1024]
  const float* Wo = (const float*)d_in[4];  // [1024,512]
  const float* bo = (const float*)d_in[5];  // [512]
  float* out = (float*)d_out;               // [64,512,512]
  float* xi  = (float*)d_ws;                // [64,512,1024] = 128 MB scratch

  // Barrier counters in d_out head; overwritten by the final GEMM.
  unsigned int* ctr = (unsigned int*)d_out;

  const int M = BATCH * SEQ;  // 32768

  dim3 blk(256);
  hipMemsetAsync(ctr, 0, GROUPS * sizeof(unsigned int), stream);
  // xi = x @ Wi + bi
  gemm_bias<<<dim3(NHID / BN, M / BM), blk, 0, stream>>>(x, Wi, bi, xi, M, NHID, NIN);
  // sequential scan (cooperative: all 256 blocks co-resident)
  {
    const float* Wh_p = Wh;
    float* xi_p = xi;
    unsigned int* ctr_p = ctr;
    void* args[3] = {(void*)&Wh_p, (void*)&xi_p, (void*)&ctr_p};
    hipLaunchCooperativeKernel((const void*)rnn_scan_ws, dim3(GROUPS * BPG),
                               dim3(256), args, 0, stream);
  }
  // y = h @ Wo + bo
  gemm_bias<<<dim3(NOUT / BN, M / BM), blk, 0, stream>>>(xi, Wo, bo, out, M, NOUT, NHID);
}

// Round 4
// 6390.658 us; speedup vs baseline: 4.5961x; 1.3555x over previous
//
#include <hip/hip_runtime.h>
#include <math.h>

// Sizes (fixed by the problem)
#define BATCH   64
#define SEQ     512
#define NIN     512
#define NHID    1024
#define NOUT    512

// ---------------- Tiled fp32 GEMM with bias: C[M,N] = A[M,K] @ B[K,N] + bias[N]
#define BM 64
#define BN 64
#define BK 16

__global__ __launch_bounds__(256) void gemm_bias(
    const float* __restrict__ A, const float* __restrict__ B,
    const float* __restrict__ bias, float* __restrict__ C,
    int M, int N, int K) {
  __shared__ float As[BK][BM + 4];
  __shared__ float Bs[BK][BN + 4];

  const int tid = threadIdx.x;
  const int bx = blockIdx.x;
  const int by = blockIdx.y;

  const int tm = (tid / 16) * 4;
  const int tn = (tid % 16) * 4;

  const int ar = tid / 4;
  const int ac = (tid % 4) * 4;
  const int br = tid / 16;
  const int bc = (tid % 16) * 4;

  float acc[4][4] = {};

  for (int k0 = 0; k0 < K; k0 += BK) {
    float4 av = *(const float4*)&A[(size_t)(by * BM + ar) * K + k0 + ac];
    As[ac + 0][ar] = av.x;
    As[ac + 1][ar] = av.y;
    As[ac + 2][ar] = av.z;
    As[ac + 3][ar] = av.w;
    float4 bv = *(const float4*)&B[(size_t)(k0 + br) * N + bx * BN + bc];
    *(float4*)&Bs[br][bc] = bv;
    __syncthreads();

#pragma unroll
    for (int k = 0; k < BK; ++k) {
      float4 a4 = *(const float4*)&As[k][tm];
      float4 b4 = *(const float4*)&Bs[k][tn];
      float ae[4] = {a4.x, a4.y, a4.z, a4.w};
      float be[4] = {b4.x, b4.y, b4.z, b4.w};
#pragma unroll
      for (int i = 0; i < 4; ++i)
#pragma unroll
        for (int j = 0; j < 4; ++j)
          acc[i][j] += ae[i] * be[j];
    }
    __syncthreads();
  }

  const float4 bb = *(const float4*)&bias[bx * BN + tn];
#pragma unroll
  for (int i = 0; i < 4; ++i) {
    float4 o;
    o.x = acc[i][0] + bb.x;
    o.y = acc[i][1] + bb.y;
    o.z = acc[i][2] + bb.z;
    o.w = acc[i][3] + bb.w;
    *(float4*)&C[(size_t)(by * BM + tm + i) * N + bx * BN + tn] = o;
  }
}

// ---------------- Cooperative weight-stationary scan, v4 ----------------
// 256 blocks = 8 batch-groups x 32 col-chunks; 256 threads.
// Wh sliver (32 k x 4 cols as float4 w[32]) in registers; per step:
//  - stage h_{s-1} rows via PLAIN clustered float4 loads (pipelined; safe
//    because L1/L2 never hold pre-finalization row data: the only
//    pre-activation read, this thread's own xi input, is a bypassing
//    agent-scope atomic load)
//  - partial matvec over 32-k slice, swizzled-LDS k-reduction
//  - activation; h written with agent-scope (write-through) atomic store
//  - group barrier: monotonic relaxed counter, 32 participants.
#define GROUPS 8
#define BPG    32   // blocks per group (column chunks)
#define BPERG  8    // batches per group

#define FMA4(hv, wv4, accv)              \
  accv.x = fmaf(hv, wv4.x, accv.x);      \
  accv.y = fmaf(hv, wv4.y, accv.y);      \
  accv.z = fmaf(hv, wv4.z, accv.z);      \
  accv.w = fmaf(hv, wv4.w, accv.w);

__global__ __launch_bounds__(256, 1) void rnn_scan_ws(
    const float* __restrict__ Wh, float* __restrict__ xi,
    unsigned int* ctr) {
  __shared__ float hs[BPERG * NHID];   // 32 KB staged h, XOR-swizzled on k
  __shared__ float P[256 * 32];        // 32 KB partial sums

  const int tid  = threadIdx.x;
  const int bg   = blockIdx.x >> 5;   // 0..7  batch group
  const int jc   = blockIdx.x & 31;   // 0..31 column chunk (32 cols)
  const int c4   = tid & 7;           // column quad within chunk
  const int kseg = tid >> 3;          // 0..31 k-slice (32 k each)
  const int colbase = jc * 32 + c4 * 4;
  const int hswz  = (kseg & 7) << 2;        // read-side LDS swizzle (bits 5-7 of k)
  const int stswz = ((tid >> 3) & 7) << 2;  // write-side: k = tid*4 -> bits 5-7 = tid>>3
  const int ob   = tid >> 5;          // output batch (0..7)
  const int ocol = tid & 31;          // output col within chunk
  const int oc4  = ocol >> 2;
  const int oce  = ocol & 3;

  // Wh sliver in registers: 32 float4 vector loads, fully unrolled.
  float4 w[32];
#pragma unroll
  for (int kk = 0; kk < 32; ++kk)
    w[kk] = *(const float4*)&Wh[(size_t)(kseg * 32 + kk) * NHID + colbase];

  // This thread's xi/h column pointer pattern.
  float* const xrow_base =
      xi + (size_t)(bg * BPERG + ob) * SEQ * NHID + jc * 32 + ocol;

  for (int s = 0; s < SEQ; ++s) {
    // Step input (pre-activation xi): agent-scope bypassing load so the
    // pre-finalization line is NEVER cached in L1/L2. Issued early; its
    // latency hides under staging/matvec.
    float* prow = xrow_base + (size_t)s * NHID;
    const float xin = __hip_atomic_load(prow, __ATOMIC_RELAXED,
                                        __HIP_MEMORY_SCOPE_AGENT);

    float4 acc[BPERG];
#pragma unroll
    for (int b = 0; b < BPERG; ++b) acc[b] = make_float4(0.f, 0.f, 0.f, 0.f);

    if (s > 0) {
      // Stage h_{s-1} (8 rows x 1024) into swizzled LDS: plain float4 loads,
      // clustered by the compiler, all in flight simultaneously.
      const float* base =
          xi + (size_t)(bg * BPERG) * SEQ * NHID + (size_t)(s - 1) * NHID + tid * 4;
#pragma unroll
      for (int b = 0; b < BPERG; ++b) {
        float4 v = *(const float4*)(base + (size_t)b * SEQ * NHID);
        *(float4*)&hs[b * NHID + ((tid * 4) ^ stswz)] = v;
      }
      __syncthreads();

      // Partial matvec over this thread's 32-k slice.
#pragma unroll
      for (int b = 0; b < BPERG; ++b) {
#pragma unroll
        for (int kq = 0; kq < 8; ++kq) {
          const float4 h4 =
              *(const float4*)&hs[b * NHID + kseg * 32 + ((kq * 4) ^ hswz)];
          FMA4(h4.x, w[kq * 4 + 0], acc[b]);
          FMA4(h4.y, w[kq * 4 + 1], acc[b]);
          FMA4(h4.z, w[kq * 4 + 2], acc[b]);
          FMA4(h4.w, w[kq * 4 + 3], acc[b]);
        }
      }
      // NOTE: no syncthreads here — P and hs are disjoint; cross-thread P
      // reads are guarded by the syncthreads below.
    }

    // Write partials to LDS (bank-swizzled), reduce 32-way per output.
    {
      const int u = kseg * 8 + c4;
      const int sw = (((kseg & 7) ^ c4)) << 2;
#pragma unroll
      for (int b = 0; b < BPERG; ++b)
        *(float4*)&P[u * 32 + ((b * 4) ^ sw)] = acc[b];
    }
    __syncthreads();

    float sum = 0.f;
#pragma unroll
    for (int q = 0; q < 32; ++q) {
      const int uu = q * 8 + oc4;
      const int sw2 = ((q & 7) ^ oc4) << 2;
      sum += P[uu * 32 + ((ob * 4 + oce) ^ sw2)];
    }

    // Activation + in-place store of h_s (agent-scope, write-through).
    const float hn = fmaxf(tanhf(xin + sum), 0.f);
    __hip_atomic_store(prow, hn, __ATOMIC_RELAXED, __HIP_MEMORY_SCOPE_AGENT);

    // Group barrier: syncthreads drains vmcnt(0) (stores at LLC), then
    // monotonic relaxed counter at agent scope.
    __syncthreads();
    if (tid == 0) {
      __hip_atomic_fetch_add(&ctr[bg], 1u, __ATOMIC_RELAXED,
                             __HIP_MEMORY_SCOPE_AGENT);
      const unsigned int target = (unsigned int)(BPG * (s + 1));
      while (__hip_atomic_load(&ctr[bg], __ATOMIC_RELAXED,
                               __HIP_MEMORY_SCOPE_AGENT) < target)
        __builtin_amdgcn_s_sleep(1);
    }
    __syncthreads();
  }
}

extern "C" void kernel_launch(void* const* d_in, const int* in_sizes, int n_in,
                              void* d_out, int out_size, void* d_ws, size_t ws_size,
                              hipStream_t stream) {
  const float* x  = (const float*)d_in[0];  // [64,512,512]
  const float* Wi = (const float*)d_in[1];  // [512,1024]
  const float* bi = (const float*)d_in[2];  // [1024]
  const float* Wh = (const float*)d_in[3];  // [1024,1024]
  const float* Wo = (const float*)d_in[4];  // [1024,512]
  const float* bo = (const float*)d_in[5];  // [512]
  float* out = (float*)d_out;               // [64,512,512]
  float* xi  = (float*)d_ws;                // [64,512,1024] = 128 MB scratch

  // Barrier counters in d_out head; overwritten by the final GEMM.
  unsigned int* ctr = (unsigned int*)d_out;

  const int M = BATCH * SEQ;  // 32768

  dim3 blk(256);
  hipMemsetAsync(ctr, 0, GROUPS * sizeof(unsigned int), stream);
  // xi = x @ Wi + bi
  gemm_bias<<<dim3(NHID / BN, M / BM), blk, 0, stream>>>(x, Wi, bi, xi, M, NHID, NIN);
  // sequential scan (cooperative: all 256 blocks co-resident)
  {
    const float* Wh_p = Wh;
    float* xi_p = xi;
    unsigned int* ctr_p = ctr;
    void* args[3] = {(void*)&Wh_p, (void*)&xi_p, (void*)&ctr_p};
    hipLaunchCooperativeKernel((const void*)rnn_scan_ws, dim3(GROUPS * BPG),
                               dim3(256), args, 0, stream);
  }
  // y = h @ Wo + bo
  gemm_bias<<<dim3(NOUT / BN, M / BM), blk, 0, stream>>>(xi, Wo, bo, out, M, NOUT, NHID);
}

// Round 5
// 2882.856 us; speedup vs baseline: 10.1885x; 2.2168x over previous
//
#include <hip/hip_runtime.h>
#include <math.h>

// Sizes (fixed by the problem)
#define BATCH   64
#define SEQ     512
#define NIN     512
#define NHID    1024
#define NOUT    512

// ---------------- Tiled fp32 GEMM with bias: C[M,N] = A[M,K] @ B[K,N] + bias[N]
#define BM 64
#define BN 64
#define BK 16

__global__ __launch_bounds__(256) void gemm_bias(
    const float* __restrict__ A, const float* __restrict__ B,
    const float* __restrict__ bias, float* __restrict__ C,
    int M, int N, int K) {
  __shared__ float As[BK][BM + 4];
  __shared__ float Bs[BK][BN + 4];

  const int tid = threadIdx.x;
  const int bx = blockIdx.x;
  const int by = blockIdx.y;

  const int tm = (tid / 16) * 4;
  const int tn = (tid % 16) * 4;

  const int ar = tid / 4;
  const int ac = (tid % 4) * 4;
  const int br = tid / 16;
  const int bc = (tid % 16) * 4;

  float acc[4][4] = {};

  for (int k0 = 0; k0 < K; k0 += BK) {
    float4 av = *(const float4*)&A[(size_t)(by * BM + ar) * K + k0 + ac];
    As[ac + 0][ar] = av.x;
    As[ac + 1][ar] = av.y;
    As[ac + 2][ar] = av.z;
    As[ac + 3][ar] = av.w;
    float4 bv = *(const float4*)&B[(size_t)(k0 + br) * N + bx * BN + bc];
    *(float4*)&Bs[br][bc] = bv;
    __syncthreads();

#pragma unroll
    for (int k = 0; k < BK; ++k) {
      float4 a4 = *(const float4*)&As[k][tm];
      float4 b4 = *(const float4*)&Bs[k][tn];
      float ae[4] = {a4.x, a4.y, a4.z, a4.w};
      float be[4] = {b4.x, b4.y, b4.z, b4.w};
#pragma unroll
      for (int i = 0; i < 4; ++i)
#pragma unroll
        for (int j = 0; j < 4; ++j)
          acc[i][j] += ae[i] * be[j];
    }
    __syncthreads();
  }

  const float4 bb = *(const float4*)&bias[bx * BN + tn];
#pragma unroll
  for (int i = 0; i < 4; ++i) {
    float4 o;
    o.x = acc[i][0] + bb.x;
    o.y = acc[i][1] + bb.y;
    o.z = acc[i][2] + bb.z;
    o.w = acc[i][3] + bb.w;
    *(float4*)&C[(size_t)(by * BM + tm + i) * N + bx * BN + tn] = o;
  }
}

// ---------------- Cooperative weight-stationary scan, v5 ----------------
// 256 blocks = 8 batch-groups x 32 col-chunks; 256 threads.
// Same compute structure as v4. Barrier redesigned: RMW-free epoch flags.
//  - flags[g][j]: block (g,j) STOREs s+1 (relaxed agent) — no atomic RMW.
//  - groups' flag regions are 128B apart (no cross-group line sharing).
//  - wave 0 polls its group's 32 flags with ONE vector load (lane j ->
//    flag j), exits when __all(flag >= s+1).
#define GROUPS 8
#define BPG    32   // blocks per group (column chunks)
#define BPERG  8    // batches per group

#define FMA4(hv, wv4, accv)              \
  accv.x = fmaf(hv, wv4.x, accv.x);      \
  accv.y = fmaf(hv, wv4.y, accv.y);      \
  accv.z = fmaf(hv, wv4.z, accv.z);      \
  accv.w = fmaf(hv, wv4.w, accv.w);

__global__ __launch_bounds__(256, 1) void rnn_scan_ws(
    const float* __restrict__ Wh, float* __restrict__ xi,
    unsigned int* flags) {
  __shared__ float hs[BPERG * NHID];   // 32 KB staged h, XOR-swizzled on k
  __shared__ float P[256 * 32];        // 32 KB partial sums

  const int tid  = threadIdx.x;
  const int bg   = blockIdx.x >> 5;   // 0..7  batch group
  const int jc   = blockIdx.x & 31;   // 0..31 column chunk (32 cols)
  const int c4   = tid & 7;           // column quad within chunk
  const int kseg = tid >> 3;          // 0..31 k-slice (32 k each)
  const int colbase = jc * 32 + c4 * 4;
  const int hswz  = (kseg & 7) << 2;        // read-side LDS swizzle (bits 5-7 of k)
  const int stswz = ((tid >> 3) & 7) << 2;  // write-side: k = tid*4 -> bits 5-7 = tid>>3
  const int ob   = tid >> 5;          // output batch (0..7)
  const int ocol = tid & 31;          // output col within chunk
  const int oc4  = ocol >> 2;
  const int oce  = ocol & 3;

  // Wh sliver in registers: 32 float4 vector loads, fully unrolled.
  float4 w[32];
#pragma unroll
  for (int kk = 0; kk < 32; ++kk)
    w[kk] = *(const float4*)&Wh[(size_t)(kseg * 32 + kk) * NHID + colbase];

  // This thread's xi/h column pointer.
  float* const xrow_base =
      xi + (size_t)(bg * BPERG + ob) * SEQ * NHID + jc * 32 + ocol;
  // Per-group flag region: 32 uints, 128B-aligned per group.
  unsigned int* const gflags = flags + bg * 32;
  unsigned int* const myflag = gflags + jc;
  unsigned int* const pollflag = gflags + (tid & 31);

  for (int s = 0; s < SEQ; ++s) {
    // Step input (pre-activation xi): agent-scope bypassing load so the
    // pre-finalization line is NEVER cached in L1/L2. Issued early; its
    // latency hides under staging/matvec.
    float* prow = xrow_base + (size_t)s * NHID;
    const float xin = __hip_atomic_load(prow, __ATOMIC_RELAXED,
                                        __HIP_MEMORY_SCOPE_AGENT);

    float4 acc[BPERG];
#pragma unroll
    for (int b = 0; b < BPERG; ++b) acc[b] = make_float4(0.f, 0.f, 0.f, 0.f);

    if (s > 0) {
      // Stage h_{s-1} (8 rows x 1024) into swizzled LDS: plain float4 loads,
      // clustered, all in flight simultaneously. Safe: these lines are never
      // cached pre-finalization (fresh address each step; xin/h-store bypass).
      const float* base =
          xi + (size_t)(bg * BPERG) * SEQ * NHID + (size_t)(s - 1) * NHID + tid * 4;
#pragma unroll
      for (int b = 0; b < BPERG; ++b) {
        float4 v = *(const float4*)(base + (size_t)b * SEQ * NHID);
        *(float4*)&hs[b * NHID + ((tid * 4) ^ stswz)] = v;
      }
      __syncthreads();

      // Partial matvec over this thread's 32-k slice.
#pragma unroll
      for (int b = 0; b < BPERG; ++b) {
#pragma unroll
        for (int kq = 0; kq < 8; ++kq) {
          const float4 h4 =
              *(const float4*)&hs[b * NHID + kseg * 32 + ((kq * 4) ^ hswz)];
          FMA4(h4.x, w[kq * 4 + 0], acc[b]);
          FMA4(h4.y, w[kq * 4 + 1], acc[b]);
          FMA4(h4.z, w[kq * 4 + 2], acc[b]);
          FMA4(h4.w, w[kq * 4 + 3], acc[b]);
        }
      }
    }

    // Write partials to LDS (bank-swizzled), reduce 32-way per output.
    {
      const int u = kseg * 8 + c4;
      const int sw = (((kseg & 7) ^ c4)) << 2;
#pragma unroll
      for (int b = 0; b < BPERG; ++b)
        *(float4*)&P[u * 32 + ((b * 4) ^ sw)] = acc[b];
    }
    __syncthreads();

    float sum = 0.f;
#pragma unroll
    for (int q = 0; q < 32; ++q) {
      const int uu = q * 8 + oc4;
      const int sw2 = ((q & 7) ^ oc4) << 2;
      sum += P[uu * 32 + ((ob * 4 + oce) ^ sw2)];
    }

    // Activation + in-place store of h_s (agent-scope, write-through).
    const float hn = fmaxf(tanhf(xin + sum), 0.f);
    __hip_atomic_store(prow, hn, __ATOMIC_RELAXED, __HIP_MEMORY_SCOPE_AGENT);

    // ---- group barrier: epoch flags, no RMW ----
    // syncthreads drains vmcnt(0): h stores are at the coherence point
    // before the flag store issues.
    __syncthreads();
    const unsigned int target = (unsigned int)(s + 1);
    if (tid == 0)
      __hip_atomic_store(myflag, target, __ATOMIC_RELAXED,
                         __HIP_MEMORY_SCOPE_AGENT);
    if (tid < 64) {
      // Whole wave 0 polls: lane j reads flag j (lanes 32-63 duplicate).
      // One vector load per poll iteration = one round trip for all 32 flags.
      while (true) {
        unsigned int v = __hip_atomic_load(pollflag, __ATOMIC_RELAXED,
                                           __HIP_MEMORY_SCOPE_AGENT);
        if (__all(v >= target)) break;
        __builtin_amdgcn_s_sleep(1);
      }
    }
    __syncthreads();
  }
}

extern "C" void kernel_launch(void* const* d_in, const int* in_sizes, int n_in,
                              void* d_out, int out_size, void* d_ws, size_t ws_size,
                              hipStream_t stream) {
  const float* x  = (const float*)d_in[0];  // [64,512,512]
  const float* Wi = (const float*)d_in[1];  // [512,1024]
  const float* bi = (const float*)d_in[2];  // [1024]
  const float* Wh = (const float*)d_in[3];  // [1024,1024]
  const float* Wo = (const float*)d_in[4];  // [1024,512]
  const float* bo = (const float*)d_in[5];  // [512]
  float* out = (float*)d_out;               // [64,512,512]
  float* xi  = (float*)d_ws;                // [64,512,1024] = 128 MB scratch

  // Epoch flags in d_out head (8 groups x 32 x 4B = 1KB, groups 128B apart);
  // overwritten by the final GEMM. Zeroed every launch.
  unsigned int* flags = (unsigned int*)d_out;

  const int M = BATCH * SEQ;  // 32768

  dim3 blk(256);
  hipMemsetAsync(flags, 0, GROUPS * BPG * sizeof(unsigned int), stream);
  // xi = x @ Wi + bi
  gemm_bias<<<dim3(NHID / BN, M / BM), blk, 0, stream>>>(x, Wi, bi, xi, M, NHID, NIN);
  // sequential scan (cooperative: all 256 blocks co-resident)
  {
    const float* Wh_p = Wh;
    float* xi_p = xi;
    unsigned int* flags_p = flags;
    void* args[3] = {(void*)&Wh_p, (void*)&xi_p, (void*)&flags_p};
    hipLaunchCooperativeKernel((const void*)rnn_scan_ws, dim3(GROUPS * BPG),
                               dim3(256), args, 0, stream);
  }
  // y = h @ Wo + bo
  gemm_bias<<<dim3(NOUT / BN, M / BM), blk, 0, stream>>>(xi, Wo, bo, out, M, NOUT, NHID);
}